// Round 1
// baseline (538.261 us; speedup 1.0000x reference)
//
#include <hip/hip_runtime.h>
#include <math.h>

#define BDIM 256
#define TP   16      // output pixels per block (along W)
#define C_   64
#define O_   64
#define H_   128
#define W_   128
#define KK_  9
#define CKK  576     // C * KK
#define SROW 580     // padded samp row stride in floats (16B-aligned, %32==4 -> <=2-way bank)

__global__ __launch_bounds__(BDIM) void dcn_fused(
    const float* __restrict__ x,
    const float* __restrict__ w_off,
    const float* __restrict__ b_off,
    const float* __restrict__ w_mod,
    const float* __restrict__ b_mod,
    const float* __restrict__ w_reg,
    float* __restrict__ out)
{
    // samp doubles as the x staging tile in phase 0/1 (first 64*54=3456 floats)
    __shared__ __align__(16) float samp[TP * SROW];   // 37.1 KB
    __shared__ float offs[TP * 18];
    __shared__ float msk [TP * KK_];
    __shared__ int   piy [TP * KK_];
    __shared__ int   pix [TP * KK_];
    __shared__ float pwy [TP * KK_];
    __shared__ float pwx [TP * KK_];

    const int t   = threadIdx.x;
    const int blk = blockIdx.x;
    const int wo0 = (blk & 7) * TP;       // W_/TP = 8 tiles per row
    const int ho  = (blk >> 3) & 127;
    const int b   = blk >> 10;

    const float* xb = x + (size_t)b * C_ * H_ * W_;

    // ---- phase 0: stage x tile: rows ho-1..ho+1, cols wo0-1..wo0+16, all 64 ch
    // layout xt[c][r][col] = samp[c*54 + r*18 + col]
    for (int idx = t; idx < C_ * 54; idx += BDIM) {
        int c   = idx / 54;
        int rem = idx - c * 54;
        int r   = rem / 18;
        int col = rem - r * 18;
        int gr  = ho - 1 + r;
        int gc  = wo0 - 1 + col;
        float v = 0.f;
        if (gr >= 0 && gr < H_ && gc >= 0 && gc < W_)
            v = xb[(c * H_ + gr) * W_ + gc];
        samp[idx] = v;
    }
    __syncthreads();

    // ---- phase 1: offset conv (18 ch) + mask conv (9 ch), 27*16 = 432 values
    for (int v = t; v < 27 * TP; v += BDIM) {
        int oc = v >> 4;       // 0..26
        int p  = v & 15;
        const float* wrow;
        float acc;
        if (oc < 18) { wrow = w_off + oc * CKK;        acc = b_off[oc]; }
        else         { wrow = w_mod + (oc - 18) * CKK; acc = b_mod[oc - 18]; }
        for (int c = 0; c < C_; ++c) {
            const float* xt = &samp[c * 54];
            const float* wr = wrow + c * 9;
            #pragma unroll
            for (int ky = 0; ky < 3; ++ky) {
                acc = fmaf(wr[ky*3+0], xt[ky*18 + p + 0], acc);
                acc = fmaf(wr[ky*3+1], xt[ky*18 + p + 1], acc);
                acc = fmaf(wr[ky*3+2], xt[ky*18 + p + 2], acc);
            }
        }
        if (oc < 18) offs[p * 18 + oc] = acc;
        else         msk[p * 9 + (oc - 18)] = 2.0f / (1.0f + expf(-acc));
    }
    __syncthreads();

    // ---- phase 1.5: sampling positions + bilinear weights (144 entries)
    if (t < TP * KK_) {
        int p  = t / 9;
        int kk = t - p * 9;
        int ky = kk / 3, kx = kk - ky * 3;
        float dy = offs[p * 18 + 2 * kk];
        float dx = offs[p * 18 + 2 * kk + 1];
        float py = dy + (float)(ho - 1 + ky);
        float px = dx + (float)(wo0 + p - 1 + kx);
        float y0f = floorf(py);
        float x0f = floorf(px);
        piy[t] = (int)y0f;
        pix[t] = (int)x0f;
        pwy[t] = py - y0f;
        pwx[t] = px - x0f;
    }
    __syncthreads();

    // ---- phase 2: bilinear gather * mask -> samp[p][c*9+kk] (overwrites x tile)
    {
        int p = t >> 4;                       // 0..15, uniform per 16-lane group
        for (int i = (t & 15); i < CKK; i += 16) {
            int c  = i / 9;
            int kk = i - c * 9;
            int e  = p * 9 + kk;
            int y0 = piy[e], x0 = pix[e];
            float wy = pwy[e], wx = pwx[e];
            const float* xc = xb + c * (H_ * W_);
            int y1 = y0 + 1, x1 = x0 + 1;
            bool yi0 = (y0 >= 0) & (y0 < H_);
            bool yi1 = (y1 >= 0) & (y1 < H_);
            bool xi0 = (x0 >= 0) & (x0 < W_);
            bool xi1 = (x1 >= 0) & (x1 < W_);
            float v00 = (yi0 & xi0) ? xc[y0 * W_ + x0] : 0.f;
            float v01 = (yi0 & xi1) ? xc[y0 * W_ + x1] : 0.f;
            float v10 = (yi1 & xi0) ? xc[y1 * W_ + x0] : 0.f;
            float v11 = (yi1 & xi1) ? xc[y1 * W_ + x1] : 0.f;
            float s = v00 * (1.f - wy) * (1.f - wx) + v01 * (1.f - wy) * wx
                    + v10 * wy * (1.f - wx)         + v11 * wy * wx;
            samp[p * SROW + i] = s * msk[e];
        }
    }
    __syncthreads();

    // ---- phase 3: out[p][o] = sum_ck samp[p][ck] * w_reg[o][ck]
    {
        int p  = t & 15;
        int og = t >> 4;       // 0..15; thread handles o = og, og+16, og+32, og+48
        const float* sp = &samp[p * SROW];
        float acc0 = 0.f, acc1 = 0.f, acc2 = 0.f, acc3 = 0.f;
        for (int ck = 0; ck < CKK; ck += 4) {
            float4 sv = *(const float4*)(sp + ck);
            float4 w0 = *(const float4*)(w_reg + (size_t)(og     ) * CKK + ck);
            float4 w1 = *(const float4*)(w_reg + (size_t)(og + 16) * CKK + ck);
            float4 w2 = *(const float4*)(w_reg + (size_t)(og + 32) * CKK + ck);
            float4 w3 = *(const float4*)(w_reg + (size_t)(og + 48) * CKK + ck);
            acc0 = fmaf(sv.x, w0.x, acc0); acc0 = fmaf(sv.y, w0.y, acc0);
            acc0 = fmaf(sv.z, w0.z, acc0); acc0 = fmaf(sv.w, w0.w, acc0);
            acc1 = fmaf(sv.x, w1.x, acc1); acc1 = fmaf(sv.y, w1.y, acc1);
            acc1 = fmaf(sv.z, w1.z, acc1); acc1 = fmaf(sv.w, w1.w, acc1);
            acc2 = fmaf(sv.x, w2.x, acc2); acc2 = fmaf(sv.y, w2.y, acc2);
            acc2 = fmaf(sv.z, w2.z, acc2); acc2 = fmaf(sv.w, w2.w, acc2);
            acc3 = fmaf(sv.x, w3.x, acc3); acc3 = fmaf(sv.y, w3.y, acc3);
            acc3 = fmaf(sv.z, w3.z, acc3); acc3 = fmaf(sv.w, w3.w, acc3);
        }
        size_t base = (size_t)b * O_ * H_ * W_ + (size_t)ho * W_ + wo0 + p;
        out[base + (size_t)(og     ) * (H_ * W_)] = acc0;
        out[base + (size_t)(og + 16) * (H_ * W_)] = acc1;
        out[base + (size_t)(og + 32) * (H_ * W_)] = acc2;
        out[base + (size_t)(og + 48) * (H_ * W_)] = acc3;
    }
}

extern "C" void kernel_launch(void* const* d_in, const int* in_sizes, int n_in,
                              void* d_out, int out_size, void* d_ws, size_t ws_size,
                              hipStream_t stream) {
    const float* x     = (const float*)d_in[0];
    const float* w_off = (const float*)d_in[1];
    const float* b_off = (const float*)d_in[2];
    const float* w_mod = (const float*)d_in[3];
    const float* b_mod = (const float*)d_in[4];
    const float* w_reg = (const float*)d_in[5];
    float* out = (float*)d_out;

    dim3 grid(4 * 128 * 8);   // b * ho * (W/TP)
    dim3 block(BDIM);
    dcn_fused<<<grid, block, 0, stream>>>(x, w_off, b_off, w_mod, b_mod, w_reg, out);
}

// Round 2
// 332.015 us; speedup vs baseline: 1.6212x; 1.6212x over previous
//
#include <hip/hip_runtime.h>
#include <math.h>

#define BDIM 256
#define TP   16      // output pixels per block (along W)
#define C_   64
#define O_   64
#define H_   128
#define W_   128
#define KK_  9
#define CKK  576     // C * KK
#define SROW 580     // padded samp/col row stride in floats (16B-aligned, %32==4)

__global__ __launch_bounds__(BDIM) void dcn_fused(
    const float* __restrict__ x,
    const float* __restrict__ w_off,
    const float* __restrict__ b_off,
    const float* __restrict__ w_mod,
    const float* __restrict__ b_mod,
    const float* __restrict__ w_reg,
    float* __restrict__ out)
{
    // samp serves as: phase0/1 im2col "col" matrix, then phase2/3 gathered samples
    __shared__ __align__(16) float samp[TP * SROW];   // 37.1 KB
    __shared__ float offs[TP * 18];
    __shared__ float msk [TP * KK_];
    __shared__ int   piy [TP * KK_];
    __shared__ int   pix [TP * KK_];
    __shared__ float pwy [TP * KK_];
    __shared__ float pwx [TP * KK_];

    const int t   = threadIdx.x;
    const int blk = blockIdx.x;
    const int wo0 = (blk & 7) * TP;       // W_/TP = 8 tiles per row
    const int ho  = (blk >> 3) & 127;
    const int b   = blk >> 10;

    const float* xb = x + (size_t)b * C_ * H_ * W_;

    // ---- phase 0: im2col for the regular 3x3 convs: col[p][ck] = x[c][ho-1+ky][wo0+p-1+kx]
    for (int ck = t; ck < CKK; ck += BDIM) {
        int c  = ck / 9;
        int kk = ck - c * 9;
        int ky = kk / 3, kx = kk - ky * 3;
        int gy = ho - 1 + ky;
        bool yok = (gy >= 0) & (gy < H_);
        const float* xr = xb + ((size_t)c * H_ + gy) * W_ + (wo0 - 1 + kx);
        #pragma unroll
        for (int p = 0; p < TP; ++p) {
            int gx = wo0 - 1 + kx + p;
            float v = (yok && gx >= 0 && gx < W_) ? xr[p] : 0.f;
            samp[p * SROW + ck] = v;
        }
    }
    __syncthreads();

    // ---- phase 1: offset conv (18 ch) + mask conv (9 ch) as GEMM 27x16, K=576
    // thread t = oc*8 + kh*4 + pg  (oc 0..26, kh 0..1 K-half, pg 0..3 pixel group)
    if (t < 216) {
        int oc = t >> 3;
        int kh = (t >> 2) & 1;
        int pg = t & 3;
        const float* wrow = ((oc < 18) ? (w_off + (size_t)oc * CKK)
                                       : (w_mod + (size_t)(oc - 18) * CKK)) + kh * 288;
        const float* c0 = &samp[(pg     ) * SROW + kh * 288];
        const float* c1 = &samp[(pg + 4 ) * SROW + kh * 288];
        const float* c2 = &samp[(pg + 8 ) * SROW + kh * 288];
        const float* c3 = &samp[(pg + 12) * SROW + kh * 288];
        float a0 = 0.f, a1 = 0.f, a2 = 0.f, a3 = 0.f;
        for (int k = 0; k < 288; k += 4) {
            float4 w4 = *(const float4*)(wrow + k);
            float4 s0 = *(const float4*)(c0 + k);
            float4 s1 = *(const float4*)(c1 + k);
            float4 s2 = *(const float4*)(c2 + k);
            float4 s3 = *(const float4*)(c3 + k);
            a0 = fmaf(w4.x, s0.x, a0); a0 = fmaf(w4.y, s0.y, a0);
            a0 = fmaf(w4.z, s0.z, a0); a0 = fmaf(w4.w, s0.w, a0);
            a1 = fmaf(w4.x, s1.x, a1); a1 = fmaf(w4.y, s1.y, a1);
            a1 = fmaf(w4.z, s1.z, a1); a1 = fmaf(w4.w, s1.w, a1);
            a2 = fmaf(w4.x, s2.x, a2); a2 = fmaf(w4.y, s2.y, a2);
            a2 = fmaf(w4.z, s2.z, a2); a2 = fmaf(w4.w, s2.w, a2);
            a3 = fmaf(w4.x, s3.x, a3); a3 = fmaf(w4.y, s3.y, a3);
            a3 = fmaf(w4.z, s3.z, a3); a3 = fmaf(w4.w, s3.w, a3);
        }
        // reduce across kh (t bit 2): partner always active (pairs stay within oc octet)
        a0 += __shfl_xor(a0, 4);
        a1 += __shfl_xor(a1, 4);
        a2 += __shfl_xor(a2, 4);
        a3 += __shfl_xor(a3, 4);
        if (kh == 0) {
            if (oc < 18) {
                float bias = b_off[oc];
                offs[(pg     ) * 18 + oc] = a0 + bias;
                offs[(pg + 4 ) * 18 + oc] = a1 + bias;
                offs[(pg + 8 ) * 18 + oc] = a2 + bias;
                offs[(pg + 12) * 18 + oc] = a3 + bias;
            } else {
                int mc = oc - 18;
                float bias = b_mod[mc];
                msk[(pg     ) * 9 + mc] = 2.f / (1.f + expf(-(a0 + bias)));
                msk[(pg + 4 ) * 9 + mc] = 2.f / (1.f + expf(-(a1 + bias)));
                msk[(pg + 8 ) * 9 + mc] = 2.f / (1.f + expf(-(a2 + bias)));
                msk[(pg + 12) * 9 + mc] = 2.f / (1.f + expf(-(a3 + bias)));
            }
        }
    }
    __syncthreads();

    // ---- phase 1.5: sampling positions + bilinear weights (144 entries)
    if (t < TP * KK_) {
        int p  = t / 9;
        int kk = t - p * 9;
        int ky = kk / 3, kx = kk - ky * 3;
        float dy = offs[p * 18 + 2 * kk];
        float dx = offs[p * 18 + 2 * kk + 1];
        float py = dy + (float)(ho - 1 + ky);
        float px = dx + (float)(wo0 + p - 1 + kx);
        float y0f = floorf(py);
        float x0f = floorf(px);
        piy[t] = (int)y0f;
        pix[t] = (int)x0f;
        pwy[t] = py - y0f;
        pwx[t] = px - x0f;
    }
    __syncthreads();

    // ---- phase 2: bilinear gather * mask -> samp[p][c*9+kk] (overwrites col)
    {
        int p = t >> 4;                       // 0..15, uniform per 16-lane group
        for (int i = (t & 15); i < CKK; i += 16) {
            int c  = i / 9;
            int kk = i - c * 9;
            int e  = p * 9 + kk;
            int y0 = piy[e], x0 = pix[e];
            float wy = pwy[e], wx = pwx[e];
            const float* xc = xb + (size_t)c * (H_ * W_);
            int y1 = y0 + 1, x1 = x0 + 1;
            bool yi0 = (y0 >= 0) & (y0 < H_);
            bool yi1 = (y1 >= 0) & (y1 < H_);
            bool xi0 = (x0 >= 0) & (x0 < W_);
            bool xi1 = (x1 >= 0) & (x1 < W_);
            float v00 = (yi0 & xi0) ? xc[y0 * W_ + x0] : 0.f;
            float v01 = (yi0 & xi1) ? xc[y0 * W_ + x1] : 0.f;
            float v10 = (yi1 & xi0) ? xc[y1 * W_ + x0] : 0.f;
            float v11 = (yi1 & xi1) ? xc[y1 * W_ + x1] : 0.f;
            float s = v00 * (1.f - wy) * (1.f - wx) + v01 * (1.f - wy) * wx
                    + v10 * wy * (1.f - wx)         + v11 * wy * wx;
            samp[p * SROW + i] = s * msk[e];
        }
    }
    __syncthreads();

    // ---- phase 3: out[p][o] = sum_ck samp[p][ck] * w_reg[o][ck]
    // thread t = og*16 + kq*4 + pg: 4 outputs (og+16j) x 4 pixels (pg+4i), K-quarter kq
    {
        int og = t >> 4;          // 0..15
        int kq = (t >> 2) & 3;    // 0..3
        int pg = t & 3;           // 0..3
        const float* sp0 = &samp[(pg     ) * SROW + kq * 144];
        const float* sp1 = &samp[(pg + 4 ) * SROW + kq * 144];
        const float* sp2 = &samp[(pg + 8 ) * SROW + kq * 144];
        const float* sp3 = &samp[(pg + 12) * SROW + kq * 144];
        const float* w0 = w_reg + (size_t)(og     ) * CKK + kq * 144;
        const float* w1 = w_reg + (size_t)(og + 16) * CKK + kq * 144;
        const float* w2 = w_reg + (size_t)(og + 32) * CKK + kq * 144;
        const float* w3 = w_reg + (size_t)(og + 48) * CKK + kq * 144;
        float acc[4][4];
        #pragma unroll
        for (int j = 0; j < 4; ++j)
            #pragma unroll
            for (int i = 0; i < 4; ++i) acc[j][i] = 0.f;

        for (int k = 0; k < 144; k += 4) {
            float4 wv0 = *(const float4*)(w0 + k);
            float4 wv1 = *(const float4*)(w1 + k);
            float4 wv2 = *(const float4*)(w2 + k);
            float4 wv3 = *(const float4*)(w3 + k);
            float4 sv0 = *(const float4*)(sp0 + k);
            float4 sv1 = *(const float4*)(sp1 + k);
            float4 sv2 = *(const float4*)(sp2 + k);
            float4 sv3 = *(const float4*)(sp3 + k);
            #define DOT(j, i, WV, SV) \
                acc[j][i] = fmaf(WV.x, SV.x, acc[j][i]); \
                acc[j][i] = fmaf(WV.y, SV.y, acc[j][i]); \
                acc[j][i] = fmaf(WV.z, SV.z, acc[j][i]); \
                acc[j][i] = fmaf(WV.w, SV.w, acc[j][i]);
            DOT(0,0,wv0,sv0) DOT(0,1,wv0,sv1) DOT(0,2,wv0,sv2) DOT(0,3,wv0,sv3)
            DOT(1,0,wv1,sv0) DOT(1,1,wv1,sv1) DOT(1,2,wv1,sv2) DOT(1,3,wv1,sv3)
            DOT(2,0,wv2,sv0) DOT(2,1,wv2,sv1) DOT(2,2,wv2,sv2) DOT(2,3,wv2,sv3)
            DOT(3,0,wv3,sv0) DOT(3,1,wv3,sv1) DOT(3,2,wv3,sv2) DOT(3,3,wv3,sv3)
            #undef DOT
        }
        // reduce across kq (t bits 2,3) — stays within the 16-thread og group (same wave)
        #pragma unroll
        for (int j = 0; j < 4; ++j)
            #pragma unroll
            for (int i = 0; i < 4; ++i) {
                acc[j][i] += __shfl_xor(acc[j][i], 4);
                acc[j][i] += __shfl_xor(acc[j][i], 8);
            }
        if (kq == 0) {
            size_t base = (size_t)b * O_ * H_ * W_ + (size_t)ho * W_ + wo0 + pg;
            #pragma unroll
            for (int j = 0; j < 4; ++j)
                #pragma unroll
                for (int i = 0; i < 4; ++i)
                    out[base + (size_t)(og + 16 * j) * (H_ * W_) + 4 * i] = acc[j][i];
        }
    }
}

extern "C" void kernel_launch(void* const* d_in, const int* in_sizes, int n_in,
                              void* d_out, int out_size, void* d_ws, size_t ws_size,
                              hipStream_t stream) {
    const float* x     = (const float*)d_in[0];
    const float* w_off = (const float*)d_in[1];
    const float* b_off = (const float*)d_in[2];
    const float* w_mod = (const float*)d_in[3];
    const float* b_mod = (const float*)d_in[4];
    const float* w_reg = (const float*)d_in[5];
    float* out = (float*)d_out;

    dim3 grid(4 * 128 * 8);   // b * ho * (W/TP)
    dim3 block(BDIM);
    dcn_fused<<<grid, block, 0, stream>>>(x, w_off, b_off, w_mod, b_mod, w_reg, out);
}

// Round 3
// 204.011 us; speedup vs baseline: 2.6384x; 1.6274x over previous
//
#include <hip/hip_runtime.h>
#include <math.h>

#define BDIM 256
#define TP   16
#define C_   64
#define O_   64
#define H_   128
#define W_   128
#define KK_  9
#define CKK  576
#define HW_  (H_ * W_)          // 16384
#define KKS  72                 // padded kk-block stride in shorts (144 B)
#define ROWS (KK_ * KKS)        // 648 shorts per pixel row (1296 B)

typedef short short8 __attribute__((ext_vector_type(8)));
typedef float f32x4  __attribute__((ext_vector_type(4)));

__device__ __forceinline__ unsigned short f2bf(float f) {
    unsigned int u = __float_as_uint(f);
    u += 0x7FFFu + ((u >> 16) & 1u);          // RNE (inputs finite)
    return (unsigned short)(u >> 16);
}

// ---------------- prep: pack B-operand fragments (bf16) into ws ----------------
// wB  : [4 tiles][18 ksteps][64 lanes][8]  (w_reg)   36864 shorts @ ws+0
// wO  : [2 tiles][18 ksteps][64 lanes][8]  (w_off/w_mod, pad>=27 zero) @ +36864
// logical K order: k = kk*64 + c ; fragment: k = kstep*32 + (lane>>4)*8 + j
__global__ __launch_bounds__(BDIM) void dcn_prep(
    const float* __restrict__ w_off, const float* __restrict__ w_mod,
    const float* __restrict__ w_reg, unsigned short* __restrict__ wpack)
{
    int i = blockIdx.x * BDIM + threadIdx.x;          // 0..55295
    bool isB = i < 36864;
    int r = isB ? i : i - 36864;
    int j    = r & 7;
    int lane = (r >> 3) & 63;
    int t2   = r >> 9;
    int kstep = t2 % 18;
    int tile  = t2 / 18;
    int k  = kstep * 32 + (lane >> 4) * 8 + j;
    int c  = k & 63;
    int kk = k >> 6;
    int col = tile * 16 + (lane & 15);
    float v;
    if (isB) {
        v = w_reg[(size_t)col * CKK + c * KK_ + kk];
    } else {
        if (col < 18)      v = w_off[(size_t)col * CKK + c * KK_ + kk];
        else if (col < 27) v = w_mod[(size_t)(col - 18) * CKK + c * KK_ + kk];
        else               v = 0.f;
    }
    wpack[i] = f2bf(v);
}

// ---------------- main fused kernel ----------------
__global__ __launch_bounds__(BDIM, 4) void dcn_fused(
    const float* __restrict__ x,
    const float* __restrict__ b_off,
    const float* __restrict__ b_mod,
    const unsigned short* __restrict__ wB,   // ws+0
    const unsigned short* __restrict__ wO,   // ws+36864 shorts
    float* __restrict__ out)
{
    __shared__ __align__(16) unsigned short samp_s[TP * ROWS];  // 20736 B
    __shared__ float  offs[TP * 18];
    __shared__ float  msk [TP * KK_];
    __shared__ int    off00[TP * KK_];
    __shared__ float4 wtab [TP * KK_];
    __shared__ int    piy_ [TP * KK_];
    __shared__ int    pix_ [TP * KK_];
    __shared__ int    fastf[TP * KK_];

    const int t    = threadIdx.x;
    const int wave = t >> 6;
    const int lane = t & 63;
    const int blk  = blockIdx.x;
    const int wo0  = (blk & 7) * TP;
    const int ho   = (blk >> 3) & 127;
    const int b    = blk >> 10;

    const float* xb = x + (size_t)b * C_ * HW_;

    // ---- A: bf16 im2col, kk-major padded layout: samp_s[p*ROWS + kk*KKS + c]
    for (int u = t; u < 576; u += BDIM) {
        int kk = u >> 6, c = u & 63;
        int ky = kk / 3, kx = kk - ky * 3;
        int gy = ho - 1 + ky;
        bool yok = (gy >= 0) & (gy < H_);
        int gx0 = wo0 - 1 + kx;
        unsigned short* dst = &samp_s[kk * KKS + c];
        const float* src = xb + (size_t)c * HW_ + gy * W_ + gx0;
        if (yok && gx0 >= 0 && gx0 + 15 < W_) {
            #pragma unroll
            for (int p = 0; p < TP; ++p) dst[p * ROWS] = f2bf(src[p]);
        } else {
            #pragma unroll
            for (int p = 0; p < TP; ++p) {
                int gx = gx0 + p;
                float v = (yok && gx >= 0 && gx < W_) ? src[p] : 0.f;
                dst[p * ROWS] = f2bf(v);
            }
        }
    }
    __syncthreads();

    // ---- B: offset(18)+mask(9) conv via MFMA, waves 0..1 (oc tiles of 16)
    if (wave < 2) {
        f32x4 acc = {0.f, 0.f, 0.f, 0.f};
        const unsigned short* bp = wO + ((size_t)(wave * 18) * 64 + lane) * 8;
        const int arow = (lane & 15) * ROWS + (lane >> 4) * 8;
        #pragma unroll
        for (int ks = 0; ks < 18; ++ks) {
            short8 av = *(const short8*)&samp_s[arow + (ks >> 1) * KKS + (ks & 1) * 32];
            short8 bv = *(const short8*)bp;  bp += 512;
            acc = __builtin_amdgcn_mfma_f32_16x16x32_bf16(av, bv, acc, 0, 0, 0);
        }
        int oc   = wave * 16 + (lane & 15);
        int prow = (lane >> 4) * 4;
        if (oc < 18) {
            float bias = b_off[oc];
            #pragma unroll
            for (int r = 0; r < 4; ++r) offs[(prow + r) * 18 + oc] = acc[r] + bias;
        } else if (oc < 27) {
            int mc = oc - 18;
            float bias = b_mod[mc];
            #pragma unroll
            for (int r = 0; r < 4; ++r)
                msk[(prow + r) * KK_ + mc] = 2.f / (1.f + expf(-(acc[r] + bias)));
        }
    }
    __syncthreads();

    // ---- C: positions -> folded corner weights (x mask)
    if (t < TP * KK_) {
        int p  = t / 9;
        int kk = t - p * 9;
        int ky = kk / 3, kx = kk - ky * 3;
        float dy = offs[p * 18 + 2 * kk];
        float dx = offs[p * 18 + 2 * kk + 1];
        float py = dy + (float)(ho - 1 + ky);
        float px = dx + (float)(wo0 + p - 1 + kx);
        float y0f = floorf(py), x0f = floorf(px);
        float wy = py - y0f,    wx = px - x0f;
        int y0 = (int)y0f, x0 = (int)x0f;
        float m = msk[p * KK_ + kk];
        float4 wt;
        wt.x = (1.f - wy) * (1.f - wx) * m;
        wt.y = (1.f - wy) * wx * m;
        wt.z = wy * (1.f - wx) * m;
        wt.w = wy * wx * m;
        wtab[t]  = wt;
        off00[t] = y0 * W_ + x0;
        piy_[t]  = y0;
        pix_[t]  = x0;
        fastf[t] = (y0 >= 0) & (y0 <= H_ - 2) & (x0 >= 0) & (x0 <= W_ - 2);
    }
    __syncthreads();

    // ---- D: bilinear gather * folded weights -> bf16 samples (overwrites samp_s)
    for (int u = t; u < 576; u += BDIM) {
        int e  = u >> 2;
        int cq = u & 3;                       // 16-channel quarter
        int p  = e / 9;
        int kk = e - p * 9;
        float4 wt = wtab[e];
        int o00   = off00[e];
        unsigned short* dst = &samp_s[p * ROWS + kk * KKS + cq * 16];
        const float* xq = xb + (size_t)(cq * 16) * HW_;
        if (fastf[e]) {
            #pragma unroll
            for (int half = 0; half < 2; ++half) {
                unsigned int pk[4];
                #pragma unroll
                for (int j = 0; j < 8; ++j) {
                    const float* q = xq + (size_t)(half * 8 + j) * HW_ + o00;
                    float s = q[0] * wt.x;
                    s = fmaf(q[1],      wt.y, s);
                    s = fmaf(q[W_],     wt.z, s);
                    s = fmaf(q[W_ + 1], wt.w, s);
                    unsigned short h = f2bf(s);
                    if (j & 1) pk[j >> 1] |= (unsigned int)h << 16;
                    else       pk[j >> 1]  = h;
                }
                uint4 v = make_uint4(pk[0], pk[1], pk[2], pk[3]);
                *(uint4*)(dst + half * 8) = v;
            }
        } else {
            int y0 = piy_[e], x0 = pix_[e];
            bool yi0 = (y0 >= 0) & (y0 < H_);
            bool yi1 = (y0 + 1 >= 0) & (y0 + 1 < H_);
            bool xi0 = (x0 >= 0) & (x0 < W_);
            bool xi1 = (x0 + 1 >= 0) & (x0 + 1 < W_);
            #pragma unroll
            for (int half = 0; half < 2; ++half) {
                unsigned int pk[4];
                #pragma unroll
                for (int j = 0; j < 8; ++j) {
                    const float* q = xq + (size_t)(half * 8 + j) * HW_;
                    float v00 = (yi0 && xi0) ? q[o00]          : 0.f;
                    float v01 = (yi0 && xi1) ? q[o00 + 1]      : 0.f;
                    float v10 = (yi1 && xi0) ? q[o00 + W_]     : 0.f;
                    float v11 = (yi1 && xi1) ? q[o00 + W_ + 1] : 0.f;
                    float s = v00 * wt.x;
                    s = fmaf(v01, wt.y, s);
                    s = fmaf(v10, wt.z, s);
                    s = fmaf(v11, wt.w, s);
                    unsigned short h = f2bf(s);
                    if (j & 1) pk[j >> 1] |= (unsigned int)h << 16;
                    else       pk[j >> 1]  = h;
                }
                uint4 v = make_uint4(pk[0], pk[1], pk[2], pk[3]);
                *(uint4*)(dst + half * 8) = v;
            }
        }
    }
    __syncthreads();

    // ---- E: out[p][o] via MFMA, wave w -> o-tile w
    {
        f32x4 acc = {0.f, 0.f, 0.f, 0.f};
        const unsigned short* bp = wB + ((size_t)(wave * 18) * 64 + lane) * 8;
        const int arow = (lane & 15) * ROWS + (lane >> 4) * 8;
        #pragma unroll
        for (int ks = 0; ks < 18; ++ks) {
            short8 av = *(const short8*)&samp_s[arow + (ks >> 1) * KKS + (ks & 1) * 32];
            short8 bv = *(const short8*)bp;  bp += 512;
            acc = __builtin_amdgcn_mfma_f32_16x16x32_bf16(av, bv, acc, 0, 0, 0);
        }
        int o    = wave * 16 + (lane & 15);
        int prow = (lane >> 4) * 4;
        float* ob = out + (size_t)b * O_ * HW_ + (size_t)o * HW_ + ho * W_ + wo0;
        #pragma unroll
        for (int r = 0; r < 4; ++r) ob[prow + r] = acc[r];
    }
}

extern "C" void kernel_launch(void* const* d_in, const int* in_sizes, int n_in,
                              void* d_out, int out_size, void* d_ws, size_t ws_size,
                              hipStream_t stream) {
    const float* x     = (const float*)d_in[0];
    const float* w_off = (const float*)d_in[1];
    const float* b_off = (const float*)d_in[2];
    const float* w_mod = (const float*)d_in[3];
    const float* b_mod = (const float*)d_in[4];
    const float* w_reg = (const float*)d_in[5];
    float* out = (float*)d_out;

    unsigned short* wpack = (unsigned short*)d_ws;        // wB @0, wO @36864
    dcn_prep<<<216, BDIM, 0, stream>>>(w_off, w_mod, w_reg, wpack);
    dcn_fused<<<4 * 128 * 8, BDIM, 0, stream>>>(x, b_off, b_mod,
                                                wpack, wpack + 36864, out);
}

// Round 4
// 88.807 us; speedup vs baseline: 6.0610x; 2.2973x over previous
//
#include <hip/hip_runtime.h>
#include <math.h>

#define BDIM 256
#define TP   16
#define C_   64
#define O_   64
#define H_   128
#define W_   128
#define KK_  9
#define CKK  576
#define HW_  (H_ * W_)          // 16384
#define KKS  72                 // padded kk-block stride in shorts (144 B)
#define ROWS (KK_ * KKS)        // 648 shorts per pixel row (1296 B)

#define WPACK_SHORTS 55296
#define XHWC_OFF     131072                         // byte offset of x_hwc in ws
#define WS_NEEDED    (XHWC_OFF + (size_t)4 * HW_ * C_ * 4)

typedef short short8 __attribute__((ext_vector_type(8)));
typedef float f32x4  __attribute__((ext_vector_type(4)));

__device__ __forceinline__ unsigned short f2bf(float f) {
    unsigned int u = __float_as_uint(f);
    u += 0x7FFFu + ((u >> 16) & 1u);          // RNE (inputs finite)
    return (unsigned short)(u >> 16);
}

// ---------------- prep: pack B-operand fragments (bf16) into ws ----------------
// wB : [4 tiles][18 ksteps][64 lanes][8]  (w_reg)   36864 shorts @ ws+0
// wO : [2 tiles][18 ksteps][64 lanes][8]  (w_off/w_mod, cols>=27 zero) @ +36864
// logical K order: k = kk*64 + c ; fragment: k = kstep*32 + (lane>>4)*8 + j
__global__ __launch_bounds__(BDIM) void dcn_prep(
    const float* __restrict__ w_off, const float* __restrict__ w_mod,
    const float* __restrict__ w_reg, unsigned short* __restrict__ wpack)
{
    int i = blockIdx.x * BDIM + threadIdx.x;          // 0..55295
    bool isB = i < 36864;
    int r = isB ? i : i - 36864;
    int j    = r & 7;
    int lane = (r >> 3) & 63;
    int t2   = r >> 9;
    int kstep = t2 % 18;
    int tile  = t2 / 18;
    int k  = kstep * 32 + (lane >> 4) * 8 + j;
    int c  = k & 63;
    int kk = k >> 6;
    int col = tile * 16 + (lane & 15);
    float v;
    if (isB) {
        v = w_reg[(size_t)col * CKK + c * KK_ + kk];
    } else {
        if (col < 18)      v = w_off[(size_t)col * CKK + c * KK_ + kk];
        else if (col < 27) v = w_mod[(size_t)(col - 18) * CKK + c * KK_ + kk];
        else               v = 0.f;
    }
    wpack[i] = f2bf(v);
}

// ---------------- transpose: x NCHW -> x_hwc [b][y*W+x][c] fp32 ----------------
__global__ __launch_bounds__(BDIM) void dcn_tr(
    const float* __restrict__ x, float* __restrict__ xh)
{
    __shared__ float tile[32][33];
    int wq = blockIdx.x & 3;           // W/32
    int cq = (blockIdx.x >> 2) & 1;    // C/32
    int by = blockIdx.x >> 3;          // b*H + y
    int b = by >> 7, y = by & 127;
    int w0 = wq * 32, c0 = cq * 32;
    int tw = threadIdx.x & 31, tc = threadIdx.x >> 5;   // 8 c/w rows per pass
    const float* xp = x + (size_t)b * C_ * HW_ + (size_t)y * W_;
    #pragma unroll
    for (int k = 0; k < 4; ++k)
        tile[tc + k * 8][tw] = xp[(size_t)(c0 + tc + k * 8) * HW_ + w0 + tw];
    __syncthreads();
    float* op = xh + ((size_t)b * HW_ + (size_t)y * W_) * C_;
    #pragma unroll
    for (int k = 0; k < 4; ++k)
        op[(size_t)(w0 + tc + k * 8) * C_ + c0 + tw] = tile[tw][tc + k * 8];
}

// ---------------- main fused kernel (HWC gather path) ----------------
__global__ __launch_bounds__(BDIM, 5) void dcn_fused_hwc(
    const float* __restrict__ xh,
    const float* __restrict__ b_off,
    const float* __restrict__ b_mod,
    const unsigned short* __restrict__ wB,
    const unsigned short* __restrict__ wO,
    float* __restrict__ out)
{
    __shared__ __align__(16) unsigned short samp_s[TP * ROWS];  // 20736 B
    __shared__ float  offs[TP * 18];
    __shared__ float  msk [TP * KK_];
    __shared__ float4 wtab[TP * KK_];
    __shared__ int4   itab[TP * KK_];

    const int t    = threadIdx.x;
    const int wave = t >> 6;
    const int lane = t & 63;
    const int blk  = blockIdx.x;
    const int wo0  = (blk & 7) * TP;
    const int ho   = (blk >> 3) & 127;
    const int b    = blk >> 10;

    const float* xb = xh + (size_t)b * HW_ * C_;

    // ---- A: bf16 im2col from HWC: samp_s[p*ROWS + kk*KKS + c], lanes over c
    {
        const int c2 = (lane & 31) * 2;
        #pragma unroll
        for (int it = 0; it < 18; ++it) {
            int e  = wave * 36 + it * 2 + (lane >> 5);
            int p  = e / 9;
            int kk = e - p * 9;
            int ky = kk / 3, kx = kk - ky * 3;
            int gy = ho - 1 + ky;
            int gx = wo0 + p - 1 + kx;
            bool ok = (gy >= 0) & (gy < H_) & (gx >= 0) & (gx < W_);
            float2 v = make_float2(0.f, 0.f);
            if (ok) v = *(const float2*)&xb[(size_t)(gy * W_ + gx) * C_ + c2];
            unsigned int pk = (unsigned int)f2bf(v.x) | ((unsigned int)f2bf(v.y) << 16);
            *(unsigned int*)&samp_s[p * ROWS + kk * KKS + c2] = pk;
        }
    }
    __syncthreads();

    // ---- B: offset(18)+mask(9) conv via MFMA, waves 0..1
    if (wave < 2) {
        f32x4 acc = {0.f, 0.f, 0.f, 0.f};
        const unsigned short* bp = wO + ((size_t)(wave * 18) * 64 + lane) * 8;
        const int arow = (lane & 15) * ROWS + (lane >> 4) * 8;
        #pragma unroll
        for (int ks = 0; ks < 18; ++ks) {
            short8 av = *(const short8*)&samp_s[arow + (ks >> 1) * KKS + (ks & 1) * 32];
            short8 bv = *(const short8*)bp;  bp += 512;
            acc = __builtin_amdgcn_mfma_f32_16x16x32_bf16(av, bv, acc, 0, 0, 0);
        }
        int oc   = wave * 16 + (lane & 15);
        int prow = (lane >> 4) * 4;
        if (oc < 18) {
            float bias = b_off[oc];
            #pragma unroll
            for (int r = 0; r < 4; ++r) offs[(prow + r) * 18 + oc] = acc[r] + bias;
        } else if (oc < 27) {
            int mc = oc - 18;
            float bias = b_mod[mc];
            #pragma unroll
            for (int r = 0; r < 4; ++r)
                msk[(prow + r) * KK_ + mc] = 2.f / (1.f + expf(-(acc[r] + bias)));
        }
    }
    __syncthreads();

    // ---- C: positions -> folded (valid x mask x bilinear) corner weights + clamped idx
    if (t < TP * KK_) {
        int p  = t / 9;
        int kk = t - p * 9;
        int ky = kk / 3, kx = kk - ky * 3;
        float dy = offs[p * 18 + 2 * kk];
        float dx = offs[p * 18 + 2 * kk + 1];
        float py = dy + (float)(ho - 1 + ky);
        float px = dx + (float)(wo0 + p - 1 + kx);
        float y0f = floorf(py), x0f = floorf(px);
        float wy = py - y0f,    wx = px - x0f;
        int y0 = (int)y0f, x0 = (int)x0f;
        int y1 = y0 + 1,   x1 = x0 + 1;
        float m = msk[p * KK_ + kk];
        float vy0 = (y0 >= 0 && y0 < H_) ? 1.f : 0.f;
        float vy1 = (y1 >= 0 && y1 < H_) ? 1.f : 0.f;
        float vx0 = (x0 >= 0 && x0 < W_) ? 1.f : 0.f;
        float vx1 = (x1 >= 0 && x1 < W_) ? 1.f : 0.f;
        float4 wt;
        wt.x = (1.f - wy) * (1.f - wx) * m * vy0 * vx0;
        wt.y = (1.f - wy) * wx * m * vy0 * vx1;
        wt.z = wy * (1.f - wx) * m * vy1 * vx0;
        wt.w = wy * wx * m * vy1 * vx1;
        int yc0 = min(max(y0, 0), H_ - 1), yc1 = min(max(y1, 0), H_ - 1);
        int xc0 = min(max(x0, 0), W_ - 1), xc1 = min(max(x1, 0), W_ - 1);
        wtab[t] = wt;
        itab[t] = make_int4(yc0 * W_ + xc0, yc0 * W_ + xc1,
                            yc1 * W_ + xc0, yc1 * W_ + xc1);
    }
    __syncthreads();

    // ---- D: bilinear gather from HWC (lanes over channels, branchless)
    {
        const int c2 = (lane & 31) * 2;
        const float* base = xb + c2;
        #pragma unroll
        for (int it = 0; it < 18; ++it) {
            int e  = wave * 36 + it * 2 + (lane >> 5);
            int p  = e / 9;
            int kk = e - p * 9;
            float4 wt = wtab[e];
            int4   ix = itab[e];
            float2 v00 = *(const float2*)(base + (size_t)ix.x * C_);
            float2 v01 = *(const float2*)(base + (size_t)ix.y * C_);
            float2 v10 = *(const float2*)(base + (size_t)ix.z * C_);
            float2 v11 = *(const float2*)(base + (size_t)ix.w * C_);
            float s0 = v00.x * wt.x;
            s0 = fmaf(v01.x, wt.y, s0);
            s0 = fmaf(v10.x, wt.z, s0);
            s0 = fmaf(v11.x, wt.w, s0);
            float s1 = v00.y * wt.x;
            s1 = fmaf(v01.y, wt.y, s1);
            s1 = fmaf(v10.y, wt.z, s1);
            s1 = fmaf(v11.y, wt.w, s1);
            unsigned int pk = (unsigned int)f2bf(s0) | ((unsigned int)f2bf(s1) << 16);
            *(unsigned int*)&samp_s[p * ROWS + kk * KKS + c2] = pk;
        }
    }
    __syncthreads();

    // ---- E: out[p][o] via MFMA, wave w -> o-tile w
    {
        f32x4 acc = {0.f, 0.f, 0.f, 0.f};
        const unsigned short* bp = wB + ((size_t)(wave * 18) * 64 + lane) * 8;
        const int arow = (lane & 15) * ROWS + (lane >> 4) * 8;
        #pragma unroll
        for (int ks = 0; ks < 18; ++ks) {
            short8 av = *(const short8*)&samp_s[arow + (ks >> 1) * KKS + (ks & 1) * 32];
            short8 bv = *(const short8*)bp;  bp += 512;
            acc = __builtin_amdgcn_mfma_f32_16x16x32_bf16(av, bv, acc, 0, 0, 0);
        }
        int o    = wave * 16 + (lane & 15);
        int prow = (lane >> 4) * 4;
        float* ob = out + (size_t)b * O_ * HW_ + (size_t)o * HW_ + ho * W_ + wo0;
        #pragma unroll
        for (int r = 0; r < 4; ++r) ob[prow + r] = acc[r];
    }
}

// ---------------- fallback (R3 NCHW path, used only if ws too small) ----------------
__global__ __launch_bounds__(BDIM, 4) void dcn_fused_nchw(
    const float* __restrict__ x,
    const float* __restrict__ b_off,
    const float* __restrict__ b_mod,
    const unsigned short* __restrict__ wB,
    const unsigned short* __restrict__ wO,
    float* __restrict__ out)
{
    __shared__ __align__(16) unsigned short samp_s[TP * ROWS];
    __shared__ float  offs[TP * 18];
    __shared__ float  msk [TP * KK_];
    __shared__ int    off00[TP * KK_];
    __shared__ float4 wtab [TP * KK_];
    __shared__ int    piy_ [TP * KK_];
    __shared__ int    pix_ [TP * KK_];
    __shared__ int    fastf[TP * KK_];

    const int t    = threadIdx.x;
    const int wave = t >> 6;
    const int lane = t & 63;
    const int blk  = blockIdx.x;
    const int wo0  = (blk & 7) * TP;
    const int ho   = (blk >> 3) & 127;
    const int b    = blk >> 10;
    const float* xb = x + (size_t)b * C_ * HW_;

    for (int u = t; u < 576; u += BDIM) {
        int kk = u >> 6, c = u & 63;
        int ky = kk / 3, kx = kk - ky * 3;
        int gy = ho - 1 + ky;
        bool yok = (gy >= 0) & (gy < H_);
        int gx0 = wo0 - 1 + kx;
        unsigned short* dst = &samp_s[kk * KKS + c];
        const float* src = xb + (size_t)c * HW_ + gy * W_ + gx0;
        #pragma unroll
        for (int p = 0; p < TP; ++p) {
            int gx = gx0 + p;
            float v = (yok && gx >= 0 && gx < W_) ? src[p] : 0.f;
            dst[p * ROWS] = f2bf(v);
        }
    }
    __syncthreads();

    if (wave < 2) {
        f32x4 acc = {0.f, 0.f, 0.f, 0.f};
        const unsigned short* bp = wO + ((size_t)(wave * 18) * 64 + lane) * 8;
        const int arow = (lane & 15) * ROWS + (lane >> 4) * 8;
        #pragma unroll
        for (int ks = 0; ks < 18; ++ks) {
            short8 av = *(const short8*)&samp_s[arow + (ks >> 1) * KKS + (ks & 1) * 32];
            short8 bv = *(const short8*)bp;  bp += 512;
            acc = __builtin_amdgcn_mfma_f32_16x16x32_bf16(av, bv, acc, 0, 0, 0);
        }
        int oc   = wave * 16 + (lane & 15);
        int prow = (lane >> 4) * 4;
        if (oc < 18) {
            float bias = b_off[oc];
            #pragma unroll
            for (int r = 0; r < 4; ++r) offs[(prow + r) * 18 + oc] = acc[r] + bias;
        } else if (oc < 27) {
            int mc = oc - 18;
            float bias = b_mod[mc];
            #pragma unroll
            for (int r = 0; r < 4; ++r)
                msk[(prow + r) * KK_ + mc] = 2.f / (1.f + expf(-(acc[r] + bias)));
        }
    }
    __syncthreads();

    if (t < TP * KK_) {
        int p  = t / 9;
        int kk = t - p * 9;
        int ky = kk / 3, kx = kk - ky * 3;
        float dy = offs[p * 18 + 2 * kk];
        float dx = offs[p * 18 + 2 * kk + 1];
        float py = dy + (float)(ho - 1 + ky);
        float px = dx + (float)(wo0 + p - 1 + kx);
        float y0f = floorf(py), x0f = floorf(px);
        float wy = py - y0f,    wx = px - x0f;
        int y0 = (int)y0f, x0 = (int)x0f;
        float m = msk[p * KK_ + kk];
        float4 wt;
        wt.x = (1.f - wy) * (1.f - wx) * m;
        wt.y = (1.f - wy) * wx * m;
        wt.z = wy * (1.f - wx) * m;
        wt.w = wy * wx * m;
        wtab[t]  = wt;
        off00[t] = y0 * W_ + x0;
        piy_[t]  = y0;
        pix_[t]  = x0;
        fastf[t] = (y0 >= 0) & (y0 <= H_ - 2) & (x0 >= 0) & (x0 <= W_ - 2);
    }
    __syncthreads();

    for (int u = t; u < 576; u += BDIM) {
        int e  = u >> 2;
        int cq = u & 3;
        int p  = e / 9;
        int kk = e - p * 9;
        float4 wt = wtab[e];
        int o00   = off00[e];
        unsigned short* dst = &samp_s[p * ROWS + kk * KKS + cq * 16];
        const float* xq = xb + (size_t)(cq * 16) * HW_;
        int y0 = piy_[e], x0 = pix_[e];
        bool yi0 = (y0 >= 0) & (y0 < H_);
        bool yi1 = (y0 + 1 >= 0) & (y0 + 1 < H_);
        bool xi0 = (x0 >= 0) & (x0 < W_);
        bool xi1 = (x0 + 1 >= 0) & (x0 + 1 < W_);
        bool fast = fastf[e];
        #pragma unroll
        for (int half = 0; half < 2; ++half) {
            unsigned int pk[4];
            #pragma unroll
            for (int j = 0; j < 8; ++j) {
                const float* q = xq + (size_t)(half * 8 + j) * HW_;
                float v00, v01, v10, v11;
                if (fast) {
                    v00 = q[o00]; v01 = q[o00 + 1]; v10 = q[o00 + W_]; v11 = q[o00 + W_ + 1];
                } else {
                    v00 = (yi0 && xi0) ? q[o00]          : 0.f;
                    v01 = (yi0 && xi1) ? q[o00 + 1]      : 0.f;
                    v10 = (yi1 && xi0) ? q[o00 + W_]     : 0.f;
                    v11 = (yi1 && xi1) ? q[o00 + W_ + 1] : 0.f;
                }
                float s = v00 * wt.x;
                s = fmaf(v01, wt.y, s);
                s = fmaf(v10, wt.z, s);
                s = fmaf(v11, wt.w, s);
                unsigned short h = f2bf(s);
                if (j & 1) pk[j >> 1] |= (unsigned int)h << 16;
                else       pk[j >> 1]  = h;
            }
            *(uint4*)(dst + half * 8) = make_uint4(pk[0], pk[1], pk[2], pk[3]);
        }
    }
    __syncthreads();

    {
        f32x4 acc = {0.f, 0.f, 0.f, 0.f};
        const unsigned short* bp = wB + ((size_t)(wave * 18) * 64 + lane) * 8;
        const int arow = (lane & 15) * ROWS + (lane >> 4) * 8;
        #pragma unroll
        for (int ks = 0; ks < 18; ++ks) {
            short8 av = *(const short8*)&samp_s[arow + (ks >> 1) * KKS + (ks & 1) * 32];
            short8 bv = *(const short8*)bp;  bp += 512;
            acc = __builtin_amdgcn_mfma_f32_16x16x32_bf16(av, bv, acc, 0, 0, 0);
        }
        int o    = wave * 16 + (lane & 15);
        int prow = (lane >> 4) * 4;
        float* ob = out + (size_t)b * O_ * HW_ + (size_t)o * HW_ + ho * W_ + wo0;
        #pragma unroll
        for (int r = 0; r < 4; ++r) ob[prow + r] = acc[r];
    }
}

extern "C" void kernel_launch(void* const* d_in, const int* in_sizes, int n_in,
                              void* d_out, int out_size, void* d_ws, size_t ws_size,
                              hipStream_t stream) {
    const float* x     = (const float*)d_in[0];
    const float* w_off = (const float*)d_in[1];
    const float* b_off = (const float*)d_in[2];
    const float* w_mod = (const float*)d_in[3];
    const float* b_mod = (const float*)d_in[4];
    const float* w_reg = (const float*)d_in[5];
    float* out = (float*)d_out;

    unsigned short* wpack = (unsigned short*)d_ws;
    dcn_prep<<<216, BDIM, 0, stream>>>(w_off, w_mod, w_reg, wpack);

    if (ws_size >= WS_NEEDED) {
        float* x_hwc = (float*)((char*)d_ws + XHWC_OFF);
        dcn_tr<<<4096, BDIM, 0, stream>>>(x, x_hwc);
        dcn_fused_hwc<<<4 * 128 * 8, BDIM, 0, stream>>>(x_hwc, b_off, b_mod,
                                                        wpack, wpack + 36864, out);
    } else {
        dcn_fused_nchw<<<4 * 128 * 8, BDIM, 0, stream>>>(x, b_off, b_mod,
                                                         wpack, wpack + 36864, out);
    }
}

// Round 5
// 56.854 us; speedup vs baseline: 9.4675x; 1.5620x over previous
//
#include <hip/hip_runtime.h>
#include <math.h>

#define BDIM 256
#define TP   16
#define C_   64
#define O_   64
#define H_   128
#define W_   128
#define KK_  9
#define CKK  576
#define HW_  (H_ * W_)          // 16384
#define KKS  72                 // padded kk-block stride in shorts (144 B)
#define ROWS (KK_ * KKS)        // 648 shorts per pixel row (1296 B)
#define XTP  72                 // compact x-tile row pad (shorts)

#define XHWC_OFF     131072                         // byte offset of x_hwc in ws
typedef short short8 __attribute__((ext_vector_type(8)));
typedef float f32x4  __attribute__((ext_vector_type(4)));

__device__ __forceinline__ unsigned short f2bf(float f) {
    unsigned int u = __float_as_uint(f);
    u += 0x7FFFu + ((u >> 16) & 1u);          // RNE (inputs finite)
    return (unsigned short)(u >> 16);
}

// packed RNE: lo -> bits[15:0], hi -> bits[31:16]
__device__ __forceinline__ unsigned int pk2bf(float lo, float hi) {
    unsigned int r;
    asm("v_cvt_pk_bf16_f32 %0, %1, %2" : "=v"(r) : "v"(lo), "v"(hi));
    return r;
}

// ---------------- prep: pack B-operand fragments (bf16) into ws ----------------
// wB : [4 tiles][18 ksteps][64 lanes][8]  (w_reg)   36864 shorts @ ws+0
// wO : [2 tiles][18 ksteps][64 lanes][8]  (w_off/w_mod, cols>=27 zero) @ +36864
// logical K order: k = kk*64 + c ; fragment: k = kstep*32 + (lane>>4)*8 + j
__global__ __launch_bounds__(BDIM) void dcn_prep(
    const float* __restrict__ w_off, const float* __restrict__ w_mod,
    const float* __restrict__ w_reg, unsigned short* __restrict__ wpack)
{
    int i = blockIdx.x * BDIM + threadIdx.x;          // 0..55295
    bool isB = i < 36864;
    int r = isB ? i : i - 36864;
    int j    = r & 7;
    int lane = (r >> 3) & 63;
    int t2   = r >> 9;
    int kstep = t2 % 18;
    int tile  = t2 / 18;
    int k  = kstep * 32 + (lane >> 4) * 8 + j;
    int c  = k & 63;
    int kk = k >> 6;
    int col = tile * 16 + (lane & 15);
    float v;
    if (isB) {
        v = w_reg[(size_t)col * CKK + c * KK_ + kk];
    } else {
        if (col < 18)      v = w_off[(size_t)col * CKK + c * KK_ + kk];
        else if (col < 27) v = w_mod[(size_t)(col - 18) * CKK + c * KK_ + kk];
        else               v = 0.f;
    }
    wpack[i] = f2bf(v);
}

// ---------------- transpose: x NCHW -> x_hwc [b][y*W+x][c] fp32 ----------------
__global__ __launch_bounds__(BDIM) void dcn_tr(
    const float* __restrict__ x, float* __restrict__ xh)
{
    __shared__ float tile[32][33];
    int wq = blockIdx.x & 3;           // W/32
    int cq = (blockIdx.x >> 2) & 1;    // C/32
    int by = blockIdx.x >> 3;          // b*H + y
    int b = by >> 7, y = by & 127;
    int w0 = wq * 32, c0 = cq * 32;
    int tw = threadIdx.x & 31, tc = threadIdx.x >> 5;
    const float* xp = x + (size_t)b * C_ * HW_ + (size_t)y * W_;
    #pragma unroll
    for (int k = 0; k < 4; ++k)
        tile[tc + k * 8][tw] = xp[(size_t)(c0 + tc + k * 8) * HW_ + w0 + tw];
    __syncthreads();
    float* op = xh + ((size_t)b * HW_ + (size_t)y * W_) * C_;
    #pragma unroll
    for (int k = 0; k < 4; ++k)
        op[(size_t)(w0 + tc + k * 8) * C_ + c0 + tw] = tile[tw][tc + k * 8];
}

// ---------------- main fused kernel (HWC, compact A-tile) ----------------
__global__ __launch_bounds__(BDIM, 5) void dcn_fused_hwc(
    const float* __restrict__ xh,
    const float* __restrict__ b_off,
    const float* __restrict__ b_mod,
    const unsigned short* __restrict__ wB,
    const unsigned short* __restrict__ wO,
    float* __restrict__ out)
{
    // samp_s also hosts the compact x-tile (xt, 54*72 shorts) during phases A-B
    __shared__ __align__(16) unsigned short samp_s[TP * ROWS];  // 20736 B
    __shared__ float  offs[TP * 18];
    __shared__ float  msk [TP * KK_];
    __shared__ float4 wtab[TP * KK_];
    __shared__ int4   itab[TP * KK_];
    __shared__ int    dsttab[TP * KK_];

    const int t    = threadIdx.x;
    const int wave = t >> 6;
    const int lane = t & 63;
    const int blk  = blockIdx.x;
    const int wo0  = (blk & 7) * TP;
    const int ho   = (blk >> 3) & 127;
    const int b    = blk >> 10;

    const float* xb = xh + (size_t)b * HW_ * C_;

    // ---- A: stage compact bf16 tile xt[row=ry*18+col][c], rows ho-1..ho+1,
    //         cols wo0-1..wo0+16, 64 ch. 54*16 float4 chunks.
    {
        unsigned short* xt = samp_s;
        for (int u = t; u < 54 * 16; u += BDIM) {
            int row = u >> 4;
            int c4  = (u & 15) * 4;
            int ry  = row / 18;
            int col = row - ry * 18;
            int gy  = ho - 1 + ry;
            int gx  = wo0 - 1 + col;
            float4 v = make_float4(0.f, 0.f, 0.f, 0.f);
            if (gy >= 0 && gy < H_ && gx >= 0 && gx < W_)
                v = *(const float4*)&xb[(size_t)(gy * W_ + gx) * C_ + c4];
            uint2 pk = make_uint2(pk2bf(v.x, v.y), pk2bf(v.z, v.w));
            *(uint2*)&samp_s[row * XTP + c4] = pk;
        }
    }
    __syncthreads();

    // ---- B: offset(18)+mask(9) conv via MFMA from the compact tile
    if (wave < 2) {
        f32x4 acc = {0.f, 0.f, 0.f, 0.f};
        const unsigned short* bp = wO + ((size_t)(wave * 18) * 64 + lane) * 8;
        const unsigned short* ap = samp_s + (lane & 15) * XTP + (lane >> 4) * 8;
        #pragma unroll
        for (int ks = 0; ks < 18; ++ks) {
            const int kk = ks >> 1, ky = kk / 3, kx = kk - ky * 3;
            short8 av = *(const short8*)&ap[(ky * 18 + kx) * XTP + (ks & 1) * 32];
            short8 bv = *(const short8*)bp;  bp += 512;
            acc = __builtin_amdgcn_mfma_f32_16x16x32_bf16(av, bv, acc, 0, 0, 0);
        }
        int oc   = wave * 16 + (lane & 15);
        int prow = (lane >> 4) * 4;
        if (oc < 18) {
            float bias = b_off[oc];
            #pragma unroll
            for (int r = 0; r < 4; ++r) offs[(prow + r) * 18 + oc] = acc[r] + bias;
        } else if (oc < 27) {
            int mc = oc - 18;
            float bias = b_mod[mc];
            #pragma unroll
            for (int r = 0; r < 4; ++r)
                msk[(prow + r) * KK_ + mc] = 2.f / (1.f + expf(-(acc[r] + bias)));
        }
    }
    __syncthreads();

    // ---- C: positions -> folded (valid x mask x bilinear) weights + clamped idx
    if (t < TP * KK_) {
        int p  = t / 9;
        int kk = t - p * 9;
        int ky = kk / 3, kx = kk - ky * 3;
        float dy = offs[p * 18 + 2 * kk];
        float dx = offs[p * 18 + 2 * kk + 1];
        float py = dy + (float)(ho - 1 + ky);
        float px = dx + (float)(wo0 + p - 1 + kx);
        float y0f = floorf(py), x0f = floorf(px);
        float wy = py - y0f,    wx = px - x0f;
        int y0 = (int)y0f, x0 = (int)x0f;
        int y1 = y0 + 1,   x1 = x0 + 1;
        float m = msk[p * KK_ + kk];
        float vy0 = (y0 >= 0 && y0 < H_) ? 1.f : 0.f;
        float vy1 = (y1 >= 0 && y1 < H_) ? 1.f : 0.f;
        float vx0 = (x0 >= 0 && x0 < W_) ? 1.f : 0.f;
        float vx1 = (x1 >= 0 && x1 < W_) ? 1.f : 0.f;
        float4 wt;
        wt.x = (1.f - wy) * (1.f - wx) * m * vy0 * vx0;
        wt.y = (1.f - wy) * wx * m * vy0 * vx1;
        wt.z = wy * (1.f - wx) * m * vy1 * vx0;
        wt.w = wy * wx * m * vy1 * vx1;
        int yc0 = min(max(y0, 0), H_ - 1), yc1 = min(max(y1, 0), H_ - 1);
        int xc0 = min(max(x0, 0), W_ - 1), xc1 = min(max(x1, 0), W_ - 1);
        wtab[t] = wt;
        itab[t] = make_int4(yc0 * W_ + xc0, yc0 * W_ + xc1,
                            yc1 * W_ + xc0, yc1 * W_ + xc1);
        dsttab[t] = p * ROWS + kk * KKS;
    }
    __syncthreads();

    // ---- D: bilinear gather from HWC, 4 ch/lane, branchless
    {
        const int c4 = (lane & 15) * 4;
        const int q  = lane >> 4;
        const float* base = xb + c4;
        #pragma unroll
        for (int it = 0; it < 9; ++it) {
            int e = wave * 36 + it * 4 + q;
            float4 wt  = wtab[e];
            int4   ix  = itab[e];
            int    doq = dsttab[e];
            float4 v00 = *(const float4*)(base + (size_t)ix.x * C_);
            float4 v01 = *(const float4*)(base + (size_t)ix.y * C_);
            float4 v10 = *(const float4*)(base + (size_t)ix.z * C_);
            float4 v11 = *(const float4*)(base + (size_t)ix.w * C_);
            float s0 = v00.x * wt.x;
            s0 = fmaf(v01.x, wt.y, s0); s0 = fmaf(v10.x, wt.z, s0); s0 = fmaf(v11.x, wt.w, s0);
            float s1 = v00.y * wt.x;
            s1 = fmaf(v01.y, wt.y, s1); s1 = fmaf(v10.y, wt.z, s1); s1 = fmaf(v11.y, wt.w, s1);
            float s2 = v00.z * wt.x;
            s2 = fmaf(v01.z, wt.y, s2); s2 = fmaf(v10.z, wt.z, s2); s2 = fmaf(v11.z, wt.w, s2);
            float s3 = v00.w * wt.x;
            s3 = fmaf(v01.w, wt.y, s3); s3 = fmaf(v10.w, wt.z, s3); s3 = fmaf(v11.w, wt.w, s3);
            uint2 pk = make_uint2(pk2bf(s0, s1), pk2bf(s2, s3));
            *(uint2*)&samp_s[doq + c4] = pk;
        }
    }
    __syncthreads();

    // ---- E: out[p][o] via MFMA, wave w -> o-tile w
    {
        f32x4 acc = {0.f, 0.f, 0.f, 0.f};
        const unsigned short* bp = wB + ((size_t)(wave * 18) * 64 + lane) * 8;
        const int arow = (lane & 15) * ROWS + (lane >> 4) * 8;
        #pragma unroll
        for (int ks = 0; ks < 18; ++ks) {
            short8 av = *(const short8*)&samp_s[arow + (ks >> 1) * KKS + (ks & 1) * 32];
            short8 bv = *(const short8*)bp;  bp += 512;
            acc = __builtin_amdgcn_mfma_f32_16x16x32_bf16(av, bv, acc, 0, 0, 0);
        }
        int o    = wave * 16 + (lane & 15);
        int prow = (lane >> 4) * 4;
        float* ob = out + (size_t)b * O_ * HW_ + (size_t)o * HW_ + ho * W_ + wo0;
        #pragma unroll
        for (int r = 0; r < 4; ++r) ob[prow + r] = acc[r];
    }
}

extern "C" void kernel_launch(void* const* d_in, const int* in_sizes, int n_in,
                              void* d_out, int out_size, void* d_ws, size_t ws_size,
                              hipStream_t stream) {
    const float* x     = (const float*)d_in[0];
    const float* w_off = (const float*)d_in[1];
    const float* b_off = (const float*)d_in[2];
    const float* w_mod = (const float*)d_in[3];
    const float* b_mod = (const float*)d_in[4];
    const float* w_reg = (const float*)d_in[5];
    float* out = (float*)d_out;

    unsigned short* wpack = (unsigned short*)d_ws;
    float* x_hwc = (float*)((char*)d_ws + XHWC_OFF);

    dcn_prep<<<216, BDIM, 0, stream>>>(w_off, w_mod, w_reg, wpack);
    dcn_tr<<<4096, BDIM, 0, stream>>>(x, x_hwc);
    dcn_fused_hwc<<<4 * 128 * 8, BDIM, 0, stream>>>(x_hwc, b_off, b_mod,
                                                    wpack, wpack + 36864, out);
}

// Round 6
// 55.855 us; speedup vs baseline: 9.6368x; 1.0179x over previous
//
#include <hip/hip_runtime.h>
#include <math.h>

#define BDIM 256
#define TP   16
#define C_   64
#define O_   64
#define H_   128
#define W_   128
#define KK_  9
#define CKK  576
#define HW_  (H_ * W_)          // 16384
#define KKS  72                 // padded kk-block stride in shorts (144 B)
#define ROWS (KK_ * KKS)        // 648 shorts per pixel row (1296 B)
#define XTP  72                 // compact x-tile row pad (shorts)

#define XHWC_OFF     131072     // byte offset of x_hwc in ws
typedef short short8 __attribute__((ext_vector_type(8)));
typedef float f32x4  __attribute__((ext_vector_type(4)));

__device__ __forceinline__ unsigned short f2bf(float f) {
    unsigned int u = __float_as_uint(f);
    u += 0x7FFFu + ((u >> 16) & 1u);          // RNE (inputs finite)
    return (unsigned short)(u >> 16);
}

// packed RNE: lo -> bits[15:0], hi -> bits[31:16]
__device__ __forceinline__ unsigned int pk2bf(float lo, float hi) {
    unsigned int r;
    asm("v_cvt_pk_bf16_f32 %0, %1, %2" : "=v"(r) : "v"(lo), "v"(hi));
    return r;
}

// ---------------- pre: fused {x NCHW->HWC transpose} + {weight fragment pack} ----
// wB : [4 tiles][18 ksteps][64 lanes][8]  (w_reg)   36864 shorts @ wpack+0
// wO : [2 tiles][18 ksteps][64 lanes][8]  (w_off/w_mod, cols>=27 zero) @ +36864
// logical K order: k = kk*64 + c ; fragment: k = kstep*32 + (lane>>4)*8 + j
__global__ __launch_bounds__(BDIM) void dcn_pre(
    const float* __restrict__ x, float* __restrict__ xh,
    const float* __restrict__ w_off, const float* __restrict__ w_mod,
    const float* __restrict__ w_reg, unsigned short* __restrict__ wpack)
{
    __shared__ float tile[32][33];
    if (blockIdx.x >= 4096) {
        // ---- weight pack (216 blocks * 256 = 55296 threads)
        int i = (blockIdx.x - 4096) * BDIM + threadIdx.x;
        bool isB = i < 36864;
        int r = isB ? i : i - 36864;
        int j    = r & 7;
        int lane = (r >> 3) & 63;
        int t2   = r >> 9;
        int kstep = t2 % 18;
        int tilei = t2 / 18;
        int k  = kstep * 32 + (lane >> 4) * 8 + j;
        int c  = k & 63;
        int kk = k >> 6;
        int col = tilei * 16 + (lane & 15);
        float v;
        if (isB) {
            v = w_reg[(size_t)col * CKK + c * KK_ + kk];
        } else {
            if (col < 18)      v = w_off[(size_t)col * CKK + c * KK_ + kk];
            else if (col < 27) v = w_mod[(size_t)(col - 18) * CKK + c * KK_ + kk];
            else               v = 0.f;
        }
        wpack[i] = f2bf(v);
        return;
    }
    // ---- transpose
    int wq = blockIdx.x & 3;           // W/32
    int cq = (blockIdx.x >> 2) & 1;    // C/32
    int by = blockIdx.x >> 3;          // b*H + y
    int b = by >> 7, y = by & 127;
    int w0 = wq * 32, c0 = cq * 32;
    int tw = threadIdx.x & 31, tc = threadIdx.x >> 5;
    const float* xp = x + (size_t)b * C_ * HW_ + (size_t)y * W_;
    #pragma unroll
    for (int k = 0; k < 4; ++k)
        tile[tc + k * 8][tw] = xp[(size_t)(c0 + tc + k * 8) * HW_ + w0 + tw];
    __syncthreads();
    float* op = xh + ((size_t)b * HW_ + (size_t)y * W_) * C_;
    #pragma unroll
    for (int k = 0; k < 4; ++k)
        op[(size_t)(w0 + tc + k * 8) * C_ + c0 + tw] = tile[tw][tc + k * 8];
}

// ---------------- main fused kernel (HWC, compact A-tile, prefetched gather) ----
__global__ __launch_bounds__(BDIM, 6) void dcn_fused_hwc(
    const float* __restrict__ xh,
    const float* __restrict__ b_off,
    const float* __restrict__ b_mod,
    const unsigned short* __restrict__ wB,
    const unsigned short* __restrict__ wO,
    float* __restrict__ out)
{
    // samp_s also hosts: compact x-tile (54*72 shorts = [0..3888)) during A-B,
    // and offs/msk (floats at short-offset 4096..4960) during B-C.
    __shared__ __align__(16) unsigned short samp_s[TP * ROWS];  // 20736 B
    __shared__ __align__(16) float4 wtab[TP * KK_];             // 2304 B
    __shared__ ushort4        itab[TP * KK_];                   // 1152 B
    __shared__ unsigned short dsttab[TP * KK_];                 // 288 B

    float* offs = (float*)(samp_s + 4096);   // 288 floats
    float* msk  = offs + TP * 18;            // 144 floats

    const int t    = threadIdx.x;
    const int wave = t >> 6;
    const int lane = t & 63;
    const int blk  = blockIdx.x;
    const int wo0  = (blk & 7) * TP;
    const int ho   = (blk >> 3) & 127;
    const int b    = blk >> 10;

    const float* xb = xh + (size_t)b * HW_ * C_;

    // ---- A: stage compact bf16 tile xt[row=ry*18+col][c]
    for (int u = t; u < 54 * 16; u += BDIM) {
        int row = u >> 4;
        int c4  = (u & 15) * 4;
        int ry  = row / 18;
        int col = row - ry * 18;
        int gy  = ho - 1 + ry;
        int gx  = wo0 - 1 + col;
        float4 v = make_float4(0.f, 0.f, 0.f, 0.f);
        if (gy >= 0 && gy < H_ && gx >= 0 && gx < W_)
            v = *(const float4*)&xb[(size_t)(gy * W_ + gx) * C_ + c4];
        *(uint2*)&samp_s[row * XTP + c4] = make_uint2(pk2bf(v.x, v.y), pk2bf(v.z, v.w));
    }
    __syncthreads();

    // ---- B: offset(18)+mask(9) conv via MFMA from the compact tile
    if (wave < 2) {
        f32x4 acc = {0.f, 0.f, 0.f, 0.f};
        const unsigned short* bp = wO + ((size_t)(wave * 18) * 64 + lane) * 8;
        const unsigned short* ap = samp_s + (lane & 15) * XTP + (lane >> 4) * 8;
        #pragma unroll
        for (int ks = 0; ks < 18; ++ks) {
            const int kk = ks >> 1, ky = kk / 3, kx = kk - ky * 3;
            short8 av = *(const short8*)&ap[(ky * 18 + kx) * XTP + (ks & 1) * 32];
            short8 bv = *(const short8*)bp;  bp += 512;
            acc = __builtin_amdgcn_mfma_f32_16x16x32_bf16(av, bv, acc, 0, 0, 0);
        }
        int oc   = wave * 16 + (lane & 15);
        int prow = (lane >> 4) * 4;
        if (oc < 18) {
            float bias = b_off[oc];
            #pragma unroll
            for (int r = 0; r < 4; ++r) offs[(prow + r) * 18 + oc] = acc[r] + bias;
        } else if (oc < 27) {
            int mc = oc - 18;
            float bias = b_mod[mc];
            #pragma unroll
            for (int r = 0; r < 4; ++r)
                msk[(prow + r) * KK_ + mc] = 2.f / (1.f + expf(-(acc[r] + bias)));
        }
    }
    __syncthreads();

    // ---- C: positions -> folded (valid x mask x bilinear) weights + clamped idx
    if (t < TP * KK_) {
        int p  = t / 9;
        int kk = t - p * 9;
        int ky = kk / 3, kx = kk - ky * 3;
        float dy = offs[p * 18 + 2 * kk];
        float dx = offs[p * 18 + 2 * kk + 1];
        float py = dy + (float)(ho - 1 + ky);
        float px = dx + (float)(wo0 + p - 1 + kx);
        float y0f = floorf(py), x0f = floorf(px);
        float wy = py - y0f,    wx = px - x0f;
        int y0 = (int)y0f, x0 = (int)x0f;
        int y1 = y0 + 1,   x1 = x0 + 1;
        float m = msk[p * KK_ + kk];
        float vy0 = (y0 >= 0 && y0 < H_) ? 1.f : 0.f;
        float vy1 = (y1 >= 0 && y1 < H_) ? 1.f : 0.f;
        float vx0 = (x0 >= 0 && x0 < W_) ? 1.f : 0.f;
        float vx1 = (x1 >= 0 && x1 < W_) ? 1.f : 0.f;
        float4 wt;
        wt.x = (1.f - wy) * (1.f - wx) * m * vy0 * vx0;
        wt.y = (1.f - wy) * wx * m * vy0 * vx1;
        wt.z = wy * (1.f - wx) * m * vy1 * vx0;
        wt.w = wy * wx * m * vy1 * vx1;
        int yc0 = min(max(y0, 0), H_ - 1), yc1 = min(max(y1, 0), H_ - 1);
        int xc0 = min(max(x0, 0), W_ - 1), xc1 = min(max(x1, 0), W_ - 1);
        wtab[t] = wt;
        itab[t] = make_ushort4((unsigned short)(yc0 * W_ + xc0),
                               (unsigned short)(yc0 * W_ + xc1),
                               (unsigned short)(yc1 * W_ + xc0),
                               (unsigned short)(yc1 * W_ + xc1));
        dsttab[t] = (unsigned short)(p * ROWS + kk * KKS);
    }
    __syncthreads();

    // ---- D: bilinear gather from HWC, 4 ch/lane, depth-2 register prefetch
    {
        const int c4 = (lane & 15) * 4;
        const int q  = lane >> 4;
        const float* base = xb + c4;
        const int e0 = wave * 36 + q;

        ushort4 ix = itab[e0];
        float4 v00 = *(const float4*)(base + (size_t)ix.x * C_);
        float4 v01 = *(const float4*)(base + (size_t)ix.y * C_);
        float4 v10 = *(const float4*)(base + (size_t)ix.z * C_);
        float4 v11 = *(const float4*)(base + (size_t)ix.w * C_);
        #pragma unroll
        for (int it = 0; it < 9; ++it) {
            const int e = e0 + it * 4;
            float4 n00, n01, n10, n11;
            if (it < 8) {
                ushort4 ixn = itab[e + 4];
                n00 = *(const float4*)(base + (size_t)ixn.x * C_);
                n01 = *(const float4*)(base + (size_t)ixn.y * C_);
                n10 = *(const float4*)(base + (size_t)ixn.z * C_);
                n11 = *(const float4*)(base + (size_t)ixn.w * C_);
            }
            float4 wt = wtab[e];
            int dst = dsttab[e];
            float s0 = v00.x * wt.x;
            s0 = fmaf(v01.x, wt.y, s0); s0 = fmaf(v10.x, wt.z, s0); s0 = fmaf(v11.x, wt.w, s0);
            float s1 = v00.y * wt.x;
            s1 = fmaf(v01.y, wt.y, s1); s1 = fmaf(v10.y, wt.z, s1); s1 = fmaf(v11.y, wt.w, s1);
            float s2 = v00.z * wt.x;
            s2 = fmaf(v01.z, wt.y, s2); s2 = fmaf(v10.z, wt.z, s2); s2 = fmaf(v11.z, wt.w, s2);
            float s3 = v00.w * wt.x;
            s3 = fmaf(v01.w, wt.y, s3); s3 = fmaf(v10.w, wt.z, s3); s3 = fmaf(v11.w, wt.w, s3);
            *(uint2*)&samp_s[dst + c4] = make_uint2(pk2bf(s0, s1), pk2bf(s2, s3));
            if (it < 8) { v00 = n00; v01 = n01; v10 = n10; v11 = n11; }
        }
    }
    __syncthreads();

    // ---- E: out[p][o] via MFMA, wave w -> o-tile w
    {
        f32x4 acc = {0.f, 0.f, 0.f, 0.f};
        const unsigned short* bp = wB + ((size_t)(wave * 18) * 64 + lane) * 8;
        const int arow = (lane & 15) * ROWS + (lane >> 4) * 8;
        #pragma unroll
        for (int ks = 0; ks < 18; ++ks) {
            short8 av = *(const short8*)&samp_s[arow + (ks >> 1) * KKS + (ks & 1) * 32];
            short8 bv = *(const short8*)bp;  bp += 512;
            acc = __builtin_amdgcn_mfma_f32_16x16x32_bf16(av, bv, acc, 0, 0, 0);
        }
        int o    = wave * 16 + (lane & 15);
        int prow = (lane >> 4) * 4;
        float* ob = out + (size_t)b * O_ * HW_ + (size_t)o * HW_ + ho * W_ + wo0;
        #pragma unroll
        for (int r = 0; r < 4; ++r) ob[prow + r] = acc[r];
    }
}

extern "C" void kernel_launch(void* const* d_in, const int* in_sizes, int n_in,
                              void* d_out, int out_size, void* d_ws, size_t ws_size,
                              hipStream_t stream) {
    const float* x     = (const float*)d_in[0];
    const float* w_off = (const float*)d_in[1];
    const float* b_off = (const float*)d_in[2];
    const float* w_mod = (const float*)d_in[3];
    const float* b_mod = (const float*)d_in[4];
    const float* w_reg = (const float*)d_in[5];
    float* out = (float*)d_out;

    unsigned short* wpack = (unsigned short*)d_ws;
    float* x_hwc = (float*)((char*)d_ws + XHWC_OFF);

    dcn_pre<<<4096 + 216, BDIM, 0, stream>>>(x, x_hwc, w_off, w_mod, w_reg, wpack);
    dcn_fused_hwc<<<4 * 128 * 8, BDIM, 0, stream>>>(x_hwc, b_off, b_mod,
                                                    wpack, wpack + 36864, out);
}